// Round 1
// baseline (497.390 us; speedup 1.0000x reference)
//
#include <hip/hip_runtime.h>

// score[i] = dot(x[src[i]], W[0:512]) + dot(x[dst[i]], W[512:1024])
//          + dot(e[i],      W[1024:1536]) + b
//
// Factored: s[n]=x[n].W1, t[n]=x[n].W2 (reads x once), p[i]=e[i].W3.
// Restructured by DEPENDENCY, not by tensor:
//   kernel 1: ALL streaming row-dots (x rows -> s,t ; e rows -> p=out).
//             No gathers, no inter-kernel bubble: one launch streams the
//             full 430 MB compulsory traffic at HBM rate.
//   kernel 2: tiny gather epilogue out[i] += s[src]+t[dst]+b (~2.5 MB,
//             s/t L2-resident; latency hidden by 625-block TLP).
// Compulsory traffic ~432 MB -> ~69 us at 6.3 TB/s achievable.

constexpr int D = 512;

__device__ __forceinline__ float dot4(const float4 a, const float4 b) {
    return a.x * b.x + a.y * b.y + a.z * b.z + a.w * b.w;
}

// One wave (64 lanes) per row. Lane l covers elements [l*4, l*4+4) and
// [256+l*4, 256+l*4+4) -> each float4 load is a fully coalesced contiguous
// 1 KB wave access. Waves first grid-stride the node rows, then the edge
// rows; both loops are branch-free pure streaming.
__global__ __launch_bounds__(256) void fused_dots_kernel(
    const float* __restrict__ x, const float* __restrict__ e,
    const float* __restrict__ W, float* __restrict__ s_out,
    float* __restrict__ t_out, float* __restrict__ p_out,
    int n_nodes, int n_edges)
{
    const int lane    = threadIdx.x & 63;
    const int wave    = (blockIdx.x * blockDim.x + threadIdx.x) >> 6;
    const int n_waves = (gridDim.x * blockDim.x) >> 6;

    const float4* W4 = (const float4*)W;
    // W1 = W[0:512), W2 = W[512:1024), W3 = W[1024:1536) — registers.
    const float4 w1a = W4[lane];
    const float4 w1b = W4[64 + lane];
    const float4 w2a = W4[128 + lane];
    const float4 w2b = W4[192 + lane];
    const float4 w3a = W4[256 + lane];
    const float4 w3b = W4[320 + lane];

    // Node rows: s = x.W1, t = x.W2 (x read ONCE for both dots).
    for (int n = wave; n < n_nodes; n += n_waves) {
        const float4* xr = (const float4*)(x + (size_t)n * D);
        const float4 xa = xr[lane];
        const float4 xb = xr[64 + lane];
        float s = dot4(xa, w1a) + dot4(xb, w1b);
        float t = dot4(xa, w2a) + dot4(xb, w2b);
#pragma unroll
        for (int off = 32; off > 0; off >>= 1) {
            s += __shfl_xor(s, off, 64);
            t += __shfl_xor(t, off, 64);
        }
        if (lane == 0) {
            s_out[n] = s;
            t_out[n] = t;
        }
    }

    // Edge rows: p = e.W3, written straight into the output buffer.
    for (int i = wave; i < n_edges; i += n_waves) {
        const float4* er = (const float4*)(e + (size_t)i * D);
        const float4 ea = er[lane];
        const float4 eb = er[64 + lane];
        float p = dot4(ea, w3a) + dot4(eb, w3b);
#pragma unroll
        for (int off = 32; off > 0; off >>= 1) p += __shfl_xor(p, off, 64);
        if (lane == 0) p_out[i] = p;
    }
}

// Epilogue: one thread per edge. src/dst/out accesses are coalesced; the
// s/t gathers are random but hit a 400 KB L2-resident table.
__global__ __launch_bounds__(256) void gather_add_kernel(
    const int* __restrict__ src, const int* __restrict__ dst,
    const float* __restrict__ s_in, const float* __restrict__ t_in,
    const float* __restrict__ bp, float* __restrict__ out, int n_edges)
{
    const int i = blockIdx.x * blockDim.x + threadIdx.x;
    if (i < n_edges) {
        out[i] += s_in[src[i]] + t_in[dst[i]] + bp[0];
    }
}

extern "C" void kernel_launch(void* const* d_in, const int* in_sizes, int n_in,
                              void* d_out, int out_size, void* d_ws, size_t ws_size,
                              hipStream_t stream) {
    const float* x   = (const float*)d_in[0];
    const float* e   = (const float*)d_in[1];
    const int*   src = (const int*)d_in[2];
    const int*   dst = (const int*)d_in[3];
    const float* W   = (const float*)d_in[4];
    const float* b   = (const float*)d_in[5];

    const int n_nodes = in_sizes[0] / D;   // 50000
    const int n_edges = in_sizes[2];       // 160000

    float* s = (float*)d_ws;               // [n_nodes]
    float* t = s + n_nodes;                // [n_nodes]
    float* out = (float*)d_out;            // [n_edges]

    // 2048 blocks * 4 waves = 8192 waves over 210000 row-dots (~26/wave).
    fused_dots_kernel<<<2048, 256, 0, stream>>>(x, e, W, s, t, out,
                                                n_nodes, n_edges);
    // 625 blocks: out[i] += s[src[i]] + t[dst[i]] + b.
    const int gblocks = (n_edges + 255) / 256;
    gather_add_kernel<<<gblocks, 256, 0, stream>>>(src, dst, s, t, b, out,
                                                   n_edges);
}

// Round 2
// 487.383 us; speedup vs baseline: 1.0205x; 1.0205x over previous
//
#include <hip/hip_runtime.h>

// score[i] = dot(x[src[i]], W[0:512]) + dot(x[dst[i]], W[512:1024])
//          + dot(e[i],      W[1024:1536]) + b
// Factored: precompute per-node s[n]=x[n].W1, t[n]=x[n].W2 (reads x ONCE),
// then per-edge gather of two scalars + one coalesced e-row dot.
// Memory-bound: ~432 MB compulsory traffic -> ~69 us at 6.3 TB/s.
// R1 post-mortem: dependency-fusion + RMW epilogue regressed (+12 us);
// two-kernel split with inline gathers is the right structure. This round:
// pair processing (2 rows/wave-iter) for independent reduce chains and
// 8 B paired lane-0 stores.

constexpr int D = 512;

__device__ __forceinline__ float dot4(const float4 a, const float4 b) {
    return a.x * b.x + a.y * b.y + a.z * b.z + a.w * b.w;
}

// One wave per node pair. Lane l covers elements [l*4, l*4+4) and
// [256+l*4, 256+l*4+4) of each 512-wide row -> every float4 load is a fully
// coalesced contiguous 1 KB wave access.
__global__ __launch_bounds__(256) void node_scores_kernel(
    const float* __restrict__ x, const float* __restrict__ W,
    float* __restrict__ s_out, float* __restrict__ t_out, int n_nodes)
{
    const int lane    = threadIdx.x & 63;
    const int wave    = (blockIdx.x * blockDim.x + threadIdx.x) >> 6;
    const int n_waves = (gridDim.x * blockDim.x) >> 6;

    const float4* W4 = (const float4*)W;
    // W1 = W[0:512), W2 = W[512:1024) — held in registers across the loop.
    const float4 w1a = W4[lane];
    const float4 w1b = W4[64 + lane];
    const float4 w2a = W4[128 + lane];
    const float4 w2b = W4[192 + lane];

    for (int n0 = wave * 2; n0 < n_nodes; n0 += n_waves * 2) {
        const int  n1   = n0 + 1;
        const bool has1 = (n1 < n_nodes);   // wave-uniform

        const float4* xr0 = (const float4*)(x + (size_t)n0 * D);
        const float4 xa0 = xr0[lane];
        const float4 xb0 = xr0[64 + lane];
        float4 xa1 = {0, 0, 0, 0}, xb1 = {0, 0, 0, 0};
        if (has1) {
            const float4* xr1 = (const float4*)(x + (size_t)n1 * D);
            xa1 = xr1[lane];
            xb1 = xr1[64 + lane];
        }

        float s0 = dot4(xa0, w1a) + dot4(xb0, w1b);
        float t0 = dot4(xa0, w2a) + dot4(xb0, w2b);
        float s1 = dot4(xa1, w1a) + dot4(xb1, w1b);
        float t1 = dot4(xa1, w2a) + dot4(xb1, w2b);
        // Four independent 6-step butterflies — chains overlap in the VALU.
#pragma unroll
        for (int off = 32; off > 0; off >>= 1) {
            s0 += __shfl_xor(s0, off, 64);
            t0 += __shfl_xor(t0, off, 64);
            s1 += __shfl_xor(s1, off, 64);
            t1 += __shfl_xor(t1, off, 64);
        }
        if (lane == 0) {
            s_out[n0] = s0;
            t_out[n0] = t0;
            if (has1) {
                s_out[n1] = s1;
                t_out[n1] = t1;
            }
        }
    }
}

// One wave per edge pair. W3 fragment lives in registers. Index + node-score
// gathers (same-address wave broadcast, L2-resident 400 KB table) are issued
// before the 4 KB of e-row fetches so their latency hides underneath.
__global__ __launch_bounds__(256) void edge_scores_kernel(
    const float* __restrict__ e, const int* __restrict__ src,
    const int* __restrict__ dst, const float* __restrict__ W,
    const float* __restrict__ bp, const float* __restrict__ s_in,
    const float* __restrict__ t_in, float* __restrict__ out, int n_edges)
{
    const int lane    = threadIdx.x & 63;
    const int wave    = (blockIdx.x * blockDim.x + threadIdx.x) >> 6;
    const int n_waves = (gridDim.x * blockDim.x) >> 6;

    const float4* W4 = (const float4*)W;
    // W3 = W[1024:1536)
    const float4 w3a = W4[256 + lane];
    const float4 w3b = W4[320 + lane];
    const float bias = bp[0];

    for (int i0 = wave * 2; i0 < n_edges; i0 += n_waves * 2) {
        const int  i1   = i0 + 1;
        const bool has1 = (i1 < n_edges);   // wave-uniform

        const int si0 = src[i0];
        const int di0 = dst[i0];
        int si1 = 0, di1 = 0;
        if (has1) {
            si1 = src[i1];
            di1 = dst[i1];
        }

        const float4* er0 = (const float4*)(e + (size_t)i0 * D);
        const float4 ea0 = er0[lane];
        const float4 eb0 = er0[64 + lane];
        float4 ea1 = {0, 0, 0, 0}, eb1 = {0, 0, 0, 0};
        if (has1) {
            const float4* er1 = (const float4*)(e + (size_t)i1 * D);
            ea1 = er1[lane];
            eb1 = er1[64 + lane];
        }

        const float sv0 = s_in[si0];
        const float tv0 = t_in[di0];
        const float sv1 = has1 ? s_in[si1] : 0.0f;
        const float tv1 = has1 ? t_in[di1] : 0.0f;

        float p0 = dot4(ea0, w3a) + dot4(eb0, w3b);
        float p1 = dot4(ea1, w3a) + dot4(eb1, w3b);
#pragma unroll
        for (int off = 32; off > 0; off >>= 1) {
            p0 += __shfl_xor(p0, off, 64);
            p1 += __shfl_xor(p1, off, 64);
        }

        if (lane == 0) {
            out[i0] = p0 + sv0 + tv0 + bias;   // adjacent-pair 8 B store
            if (has1) out[i1] = p1 + sv1 + tv1 + bias;
        }
    }
}

extern "C" void kernel_launch(void* const* d_in, const int* in_sizes, int n_in,
                              void* d_out, int out_size, void* d_ws, size_t ws_size,
                              hipStream_t stream) {
    const float* x   = (const float*)d_in[0];
    const float* e   = (const float*)d_in[1];
    const int*   src = (const int*)d_in[2];
    const int*   dst = (const int*)d_in[3];
    const float* W   = (const float*)d_in[4];
    const float* b   = (const float*)d_in[5];

    const int n_nodes = in_sizes[0] / D;   // 50000
    const int n_edges = in_sizes[2];       // 160000

    float* s = (float*)d_ws;               // [n_nodes]
    float* t = s + n_nodes;                // [n_nodes]
    float* out = (float*)d_out;            // [n_edges]

    // 1024 blocks * 4 waves = 4096 waves over 25000 node pairs (~6/wave).
    node_scores_kernel<<<1024, 256, 0, stream>>>(x, W, s, t, n_nodes);
    // 2048 blocks * 4 waves = 8192 waves over 80000 edge pairs (~10/wave).
    edge_scores_kernel<<<2048, 256, 0, stream>>>(e, src, dst, W, b, s, t, out,
                                                 n_edges);
}